// Round 5
// baseline (196.980 us; speedup 1.0000x reference)
//
#include <hip/hip_runtime.h>
#include <stdint.h>

// ---------- types ----------
typedef __bf16 bf16x8 __attribute__((ext_vector_type(8)));
typedef float f32x4 __attribute__((ext_vector_type(4)));
typedef float float4v __attribute__((ext_vector_type(4)));
typedef unsigned short u16x8 __attribute__((ext_vector_type(8)));

// round-to-nearest-even fp32 -> bf16
__device__ __forceinline__ unsigned short f2bf(float f) {
    unsigned u = __float_as_uint(f);
    u += 0x7fffu + ((u >> 16) & 1u);
    return (unsigned short)(u >> 16);
}

// fast stable softplus: max(x,0) + log(1+exp(-|x|))
__device__ __forceinline__ float softplus(float x) {
    return fmaxf(x, 0.0f) + __logf(1.0f + __expf(-fabsf(x)));
}

// async global->LDS, 16B per lane (gfx950). LDS dest must be wave-uniform
// base + lane*16 (lane-ordered, contiguous).
__device__ __forceinline__ void gl_lds16(const void* gptr, void* lptr) {
    auto g = reinterpret_cast<const __attribute__((address_space(1))) void*>(
        reinterpret_cast<uintptr_t>(gptr));
    auto l = reinterpret_cast<__attribute__((address_space(3))) void*>(
        reinterpret_cast<uintptr_t>(lptr));
    __builtin_amdgcn_global_load_lds(g, l, 16, 0, 0);
}

// ---------- fused prep: input f32->bf16  AND  w = mu + softplus(rho)*eps ----
__global__ void prep_kernel(const float* __restrict__ in,
                            const float* __restrict__ mu,
                            const float* __restrict__ rho,
                            const float* __restrict__ eps,
                            unsigned short* __restrict__ in_bf,
                            unsigned short* __restrict__ w_bf,
                            int nIn8, int nW8) {
    int i = blockIdx.x * blockDim.x + threadIdx.x;
    if (i < nIn8) {
        const float4v* p = (const float4v*)in + (size_t)i * 2;
        float4v a = p[0], b = p[1];
        u16x8 r;
        r[0] = f2bf(a[0]); r[1] = f2bf(a[1]); r[2] = f2bf(a[2]); r[3] = f2bf(a[3]);
        r[4] = f2bf(b[0]); r[5] = f2bf(b[1]); r[6] = f2bf(b[2]); r[7] = f2bf(b[3]);
        ((u16x8*)in_bf)[i] = r;
    } else {
        int j = i - nIn8;
        if (j >= nW8) return;
        const float4v* pm = (const float4v*)mu  + (size_t)j * 2;
        const float4v* pr = (const float4v*)rho + (size_t)j * 2;
        const float4v* pe = (const float4v*)eps + (size_t)j * 2;
        float4v m0 = pm[0], m1 = pm[1];
        float4v r0 = pr[0], r1 = pr[1];
        float4v e0 = pe[0], e1 = pe[1];
        u16x8 r;
        r[0] = f2bf(m0[0] + softplus(r0[0]) * e0[0]);
        r[1] = f2bf(m0[1] + softplus(r0[1]) * e0[1]);
        r[2] = f2bf(m0[2] + softplus(r0[2]) * e0[2]);
        r[3] = f2bf(m0[3] + softplus(r0[3]) * e0[3]);
        r[4] = f2bf(m1[0] + softplus(r1[0]) * e1[0]);
        r[5] = f2bf(m1[1] + softplus(r1[1]) * e1[1]);
        r[6] = f2bf(m1[2] + softplus(r1[2]) * e1[2]);
        r[7] = f2bf(m1[3] + softplus(r1[3]) * e1[3]);
        ((u16x8*)w_bf)[j] = r;
    }
}

// ---------- GEMM: C[M,N] = A[M,K] * B[N,K]^T + bias, bf16 in / f32 out -----
// R5 = R3 (best: 40.3us) minus B's LDS round-trip. R3 was LDS-BW-bound:
// 192 ds_read_b128/CU-iter-pair x ~12cyc = 2304 of ~3027 cyc. The 16x16x32
// B-fragment (B[n=lane16][k=quad*8..+8]) is a CONTIGUOUS 16B row segment of
// the [N,K] weight matrix, so each wave loads its B-frags straight from
// global (L2-resident, ~30 B/cyc/CU << 56 B/cyc L2 ceiling), one iter ahead
// into registers. LDS now holds A only (double-buffered, gl_lds16, 1 barrier
// per iter as in R3). LDS reads: 12 -> 8 per lane-iter; staging halves.
// A k-groups XOR-swizzled (phys_kg = kg ^ (row&7)): 0 bank conflicts (R2/R3).
#define BM 128
#define BN 128
#define BK 64

__global__ __launch_bounds__(512, 4)
void gemm_bt_kernel(const unsigned short* __restrict__ A,   // [M,K] bf16
                    const unsigned short* __restrict__ B,   // [N,K] bf16
                    const float* __restrict__ bias,         // [N]
                    float* __restrict__ C,                  // [M,N] f32
                    int M, int N, int K) {
    __shared__ unsigned short lds_a[2][BM * BK];   // 2 x 16 KB

    const int t      = threadIdx.x;
    const int lane   = t & 63;
    const int wave   = t >> 6;          // 0..7
    const int lane16 = lane & 15;
    const int quad   = lane >> 4;       // 0..3
    const int wm     = wave & 1;        // wave row: 0..1 (64 rows each)
    const int wn     = wave >> 1;       // wave col: 0..3 (32 cols each)

    const int m0 = blockIdx.y * BM;
    const int n0 = blockIdx.x * BN;

    // A staging: 1024 16B-chunks, 512 threads -> 2 chunks each.
    // chunk c -> LDS slot c (row=c>>3, pkg=c&7); global kg = pkg ^ (row&7)
    const int r1   = t >> 3;                 // rows 0..63
    const int pkg  = t & 7;
    const int g1   = (pkg ^ (r1 & 7)) * 8;
    const int r2   = r1 + 64;                // rows 64..127
    const int g2   = (pkg ^ (r2 & 7)) * 8;

    const unsigned short* Ab = A + (size_t)m0 * K;

    // B direct-fragment pointers: row = n0 + wn*32 + ni*16 + lane16,
    // element base quad*8; per iter offset k0 + ch*32.
    const unsigned short* pB0 =
        B + (size_t)(n0 + wn * 32 + lane16) * K + quad * 8;
    const unsigned short* pB1 = pB0 + (size_t)16 * K;

    f32x4 acc[4][2] = {};
    const int sw  = lane16 & 7;   // A read-side swizzle key
    const int nit = K / BK;       // 32 (even)

    auto stageA = [&](int buf, int k0) {
        gl_lds16(Ab + (size_t)r1 * K + k0 + g1, &lds_a[buf][t * 8]);
        gl_lds16(Ab + (size_t)r2 * K + k0 + g2, &lds_a[buf][4096 + t * 8]);
    };
    auto loadB = [&](bf16x8 (&dst)[2][2], int k0) {
#pragma unroll
        for (int ch = 0; ch < 2; ch++) {
            dst[ch][0] = *(const bf16x8*)(pB0 + k0 + ch * 32);
            dst[ch][1] = *(const bf16x8*)(pB1 + k0 + ch * 32);
        }
    };

    bf16x8 bX[2][2], bY[2][2];

    // prologue
    loadB(bX, 0);
    stageA(0, 0);
    __syncthreads();

    auto body = [&](int cur, int it, bf16x8 (&bcur)[2][2], bf16x8 (&bnxt)[2][2]) {
        // (1) B-frags for next iter straight to regs (in flight across MFMA)
        if (it + 1 < nit) loadB(bnxt, (it + 1) * BK);
        // (2) A fragment reads from current LDS buffer
        bf16x8 af[2][4];
#pragma unroll
        for (int ch = 0; ch < 2; ch++) {
            const int pk = ((ch * 4 + quad) ^ sw) * 8;
#pragma unroll
            for (int mi = 0; mi < 4; mi++)
                af[ch][mi] = *(const bf16x8*)(&lds_a[cur][0] +
                               (wm * 64 + mi * 16 + lane16) * BK + pk);
        }
        // (3) async-stage next A tile into the other buffer
        if (it + 1 < nit) stageA(cur ^ 1, (it + 1) * BK);
        // (4) MFMAs on current frags
#pragma unroll
        for (int ch = 0; ch < 2; ch++)
#pragma unroll
            for (int mi = 0; mi < 4; mi++)
#pragma unroll
                for (int ni = 0; ni < 2; ni++)
                    acc[mi][ni] = __builtin_amdgcn_mfma_f32_16x16x32_bf16(
                        af[ch][mi], bcur[ch][ni], acc[mi][ni], 0, 0, 0);
        // (5) single barrier (drains staging, releases current buffer)
        __syncthreads();
    };

    for (int it = 0; it < nit; it += 2) {
        body(0, it,     bX, bY);
        body(1, it + 1, bY, bX);
    }

    // epilogue: C/D layout col=lane&15, row=quad*4+reg (m89-verified)
    float bv[2];
#pragma unroll
    for (int ni = 0; ni < 2; ni++)
        bv[ni] = bias[n0 + wn * 32 + ni * 16 + lane16];

#pragma unroll
    for (int mi = 0; mi < 4; mi++) {
        const int rbase = m0 + wm * 64 + mi * 16 + quad * 4;
#pragma unroll
        for (int ni = 0; ni < 2; ni++) {
            const int col = n0 + wn * 32 + ni * 16 + lane16;
#pragma unroll
            for (int r = 0; r < 4; r++)
                C[(size_t)(rbase + r) * N + col] = acc[mi][ni][r] + bv[ni];
        }
    }
}

extern "C" void kernel_launch(void* const* d_in, const int* in_sizes, int n_in,
                              void* d_out, int out_size, void* d_ws, size_t ws_size,
                              hipStream_t stream) {
    const float* input = (const float*)d_in[0];
    const float* mu    = (const float*)d_in[1];
    const float* rho   = (const float*)d_in[2];
    const float* eps   = (const float*)d_in[3];
    const float* bias  = (const float*)d_in[4];
    float* out = (float*)d_out;

    const int OUT = in_sizes[4];              // 2048
    const int IN  = in_sizes[1] / OUT;        // 2048
    const int M   = in_sizes[0] / IN;         // 4096

    unsigned short* in_bf = (unsigned short*)d_ws;                 // M*IN bf16
    unsigned short* w_bf  = in_bf + (size_t)M * IN;                // OUT*IN bf16

    const int nIn8 = (M * IN) / 8;
    const int nW8  = (OUT * IN) / 8;
    prep_kernel<<<dim3((nIn8 + nW8 + 255) / 256), 256, 0, stream>>>(
        input, mu, rho, eps, in_bf, w_bf, nIn8, nW8);

    gemm_bt_kernel<<<dim3(OUT / BN, M / BM), 512, 0, stream>>>(
        in_bf, w_bf, bias, out, M, OUT, IN);
}

// Round 6
// 163.013 us; speedup vs baseline: 1.2084x; 1.2084x over previous
//
#include <hip/hip_runtime.h>
#include <stdint.h>

// ---------- types ----------
typedef __bf16 bf16x8 __attribute__((ext_vector_type(8)));
typedef float f32x4 __attribute__((ext_vector_type(4)));
typedef float float4v __attribute__((ext_vector_type(4)));
typedef unsigned short u16x8 __attribute__((ext_vector_type(8)));

// round-to-nearest-even fp32 -> bf16
__device__ __forceinline__ unsigned short f2bf(float f) {
    unsigned u = __float_as_uint(f);
    u += 0x7fffu + ((u >> 16) & 1u);
    return (unsigned short)(u >> 16);
}

// fast stable softplus: max(x,0) + log(1+exp(-|x|))
__device__ __forceinline__ float softplus(float x) {
    return fmaxf(x, 0.0f) + __logf(1.0f + __expf(-fabsf(x)));
}

// async global->LDS, 16B per lane (gfx950). LDS dest must be wave-uniform
// base + lane*16 (lane-ordered, contiguous).
__device__ __forceinline__ void gl_lds16(const void* gptr, void* lptr) {
    auto g = reinterpret_cast<const __attribute__((address_space(1))) void*>(
        reinterpret_cast<uintptr_t>(gptr));
    auto l = reinterpret_cast<__attribute__((address_space(3))) void*>(
        reinterpret_cast<uintptr_t>(lptr));
    __builtin_amdgcn_global_load_lds(g, l, 16, 0, 0);
}

// ---------- fused prep: input f32->bf16  AND  w = mu + softplus(rho)*eps ----
__global__ void prep_kernel(const float* __restrict__ in,
                            const float* __restrict__ mu,
                            const float* __restrict__ rho,
                            const float* __restrict__ eps,
                            unsigned short* __restrict__ in_bf,
                            unsigned short* __restrict__ w_bf,
                            int nIn8, int nW8) {
    int i = blockIdx.x * blockDim.x + threadIdx.x;
    if (i < nIn8) {
        const float4v* p = (const float4v*)in + (size_t)i * 2;
        float4v a = p[0], b = p[1];
        u16x8 r;
        r[0] = f2bf(a[0]); r[1] = f2bf(a[1]); r[2] = f2bf(a[2]); r[3] = f2bf(a[3]);
        r[4] = f2bf(b[0]); r[5] = f2bf(b[1]); r[6] = f2bf(b[2]); r[7] = f2bf(b[3]);
        ((u16x8*)in_bf)[i] = r;
    } else {
        int j = i - nIn8;
        if (j >= nW8) return;
        const float4v* pm = (const float4v*)mu  + (size_t)j * 2;
        const float4v* pr = (const float4v*)rho + (size_t)j * 2;
        const float4v* pe = (const float4v*)eps + (size_t)j * 2;
        float4v m0 = pm[0], m1 = pm[1];
        float4v r0 = pr[0], r1 = pr[1];
        float4v e0 = pe[0], e1 = pe[1];
        u16x8 r;
        r[0] = f2bf(m0[0] + softplus(r0[0]) * e0[0]);
        r[1] = f2bf(m0[1] + softplus(r0[1]) * e0[1]);
        r[2] = f2bf(m0[2] + softplus(r0[2]) * e0[2]);
        r[3] = f2bf(m0[3] + softplus(r0[3]) * e0[3]);
        r[4] = f2bf(m1[0] + softplus(r1[0]) * e1[0]);
        r[5] = f2bf(m1[1] + softplus(r1[1]) * e1[1]);
        r[6] = f2bf(m1[2] + softplus(r1[2]) * e1[2]);
        r[7] = f2bf(m1[3] + softplus(r1[3]) * e1[3]);
        ((u16x8*)w_bf)[j] = r;
    }
}

// ---------- GEMM: C[M,N] = A[M,K] * B[N,K]^T + bias, bf16 in / f32 out -----
// R6 = R3's verified loop (dbuf LDS, gl_lds16, 1 barrier/iter, XOR swizzle)
// with wave-tile 64x64 (4x4 MFMA): 0.5 ds_read per MFMA vs R3's 0.75.
// R3 was LDS-read-pipe-bound (93% of iter cycles); this cuts LDS reads 33%
// for identical FLOPs. 128x128 tile, BK=64, 256 threads = 4 waves in 2x2.
// LDS 64 KB -> 2 blocks/CU (grid 512 caps there anyway).
// R5 lesson: fragments must NOT come direct from global (lane16 strides 4KB
// -> 16-way request amplification); both A and B stay on the LDS path.
#define BM 128
#define BN 128
#define BK 64

__global__ __launch_bounds__(256, 2)
void gemm_bt_kernel(const unsigned short* __restrict__ A,   // [M,K] bf16
                    const unsigned short* __restrict__ B,   // [N,K] bf16
                    const float* __restrict__ bias,         // [N]
                    float* __restrict__ C,                  // [M,N] f32
                    int M, int N, int K) {
    __shared__ unsigned short lds_a[2][BM * BK];   // 2 x 16 KB
    __shared__ unsigned short lds_b[2][BN * BK];   // 2 x 16 KB

    const int t      = threadIdx.x;
    const int lane   = t & 63;
    const int wave   = t >> 6;          // 0..3
    const int lane16 = lane & 15;
    const int quad   = lane >> 4;       // 0..3
    const int wm     = wave & 1;        // wave row: 0..1 (64 rows each)
    const int wn     = wave >> 1;       // wave col: 0..1 (64 cols each)

    const int m0 = blockIdx.y * BM;
    const int n0 = blockIdx.x * BN;

    // staging: each tile = 1024 16B-chunks; 256 threads -> 4 chunks each
    // (per tile). chunk c -> LDS slot c (row=c>>3, pkg=c&7);
    // global kg = pkg ^ (row&7)  [XOR swizzle, read side uses lane16&7]
    const int pkg = t & 7;
    int srow[4], sgo[4];
#pragma unroll
    for (int j = 0; j < 4; j++) {
        srow[j] = (j * 256 + t) >> 3;            // rows 0..127
        sgo[j]  = (pkg ^ (srow[j] & 7)) * 8;
    }

    const unsigned short* Ab = A + (size_t)m0 * K;
    const unsigned short* Bb = B + (size_t)n0 * K;

    f32x4 acc[4][4] = {};
    const int sw  = lane16 & 7;   // read-side swizzle key
    const int nit = K / BK;       // 32 (even)

    auto stage = [&](int buf, int k0) {
#pragma unroll
        for (int j = 0; j < 4; j++)
            gl_lds16(Ab + (size_t)srow[j] * K + k0 + sgo[j],
                     &lds_a[buf][(j * 256 + t) * 8]);
#pragma unroll
        for (int j = 0; j < 4; j++)
            gl_lds16(Bb + (size_t)srow[j] * K + k0 + sgo[j],
                     &lds_b[buf][(j * 256 + t) * 8]);
    };

    // prologue
    stage(0, 0);
    __syncthreads();

    auto body = [&](int cur, int it) {
        const unsigned short* la = lds_a[cur];
        const unsigned short* lb = lds_b[cur];
        // (1) hoist all fragment reads of current tile (16 ds_read_b128)
        bf16x8 af[2][4], bfr[2][4];
#pragma unroll
        for (int ch = 0; ch < 2; ch++) {
            const int pk = ((ch * 4 + quad) ^ sw) * 8;
#pragma unroll
            for (int mi = 0; mi < 4; mi++)
                af[ch][mi] = *(const bf16x8*)(la + (wm * 64 + mi * 16 + lane16) * BK + pk);
#pragma unroll
            for (int ni = 0; ni < 4; ni++)
                bfr[ch][ni] = *(const bf16x8*)(lb + (wn * 64 + ni * 16 + lane16) * BK + pk);
        }
        // (2) async-stage next tile into other buffer
        if (it + 1 < nit) stage(cur ^ 1, (it + 1) * BK);
        // (3) 32 MFMAs
#pragma unroll
        for (int ch = 0; ch < 2; ch++)
#pragma unroll
            for (int mi = 0; mi < 4; mi++)
#pragma unroll
                for (int ni = 0; ni < 4; ni++)
                    acc[mi][ni] = __builtin_amdgcn_mfma_f32_16x16x32_bf16(
                        af[ch][mi], bfr[ch][ni], acc[mi][ni], 0, 0, 0);
        // (4) single barrier (drains staging, releases current buffer)
        __syncthreads();
    };

    for (int it = 0; it < nit; it += 2) {
        body(0, it);
        body(1, it + 1);
    }

    // epilogue: C/D layout col=lane&15, row=quad*4+reg (m89-verified)
    float bv[4];
#pragma unroll
    for (int ni = 0; ni < 4; ni++)
        bv[ni] = bias[n0 + wn * 64 + ni * 16 + lane16];

#pragma unroll
    for (int mi = 0; mi < 4; mi++) {
        const int rbase = m0 + wm * 64 + mi * 16 + quad * 4;
#pragma unroll
        for (int ni = 0; ni < 4; ni++) {
            const int col = n0 + wn * 64 + ni * 16 + lane16;
#pragma unroll
            for (int r = 0; r < 4; r++)
                C[(size_t)(rbase + r) * N + col] = acc[mi][ni][r] + bv[ni];
        }
    }
}

extern "C" void kernel_launch(void* const* d_in, const int* in_sizes, int n_in,
                              void* d_out, int out_size, void* d_ws, size_t ws_size,
                              hipStream_t stream) {
    const float* input = (const float*)d_in[0];
    const float* mu    = (const float*)d_in[1];
    const float* rho   = (const float*)d_in[2];
    const float* eps   = (const float*)d_in[3];
    const float* bias  = (const float*)d_in[4];
    float* out = (float*)d_out;

    const int OUT = in_sizes[4];              // 2048
    const int IN  = in_sizes[1] / OUT;        // 2048
    const int M   = in_sizes[0] / IN;         // 4096

    unsigned short* in_bf = (unsigned short*)d_ws;                 // M*IN bf16
    unsigned short* w_bf  = in_bf + (size_t)M * IN;                // OUT*IN bf16

    const int nIn8 = (M * IN) / 8;
    const int nW8  = (OUT * IN) / 8;
    prep_kernel<<<dim3((nIn8 + nW8 + 255) / 256), 256, 0, stream>>>(
        input, mu, rho, eps, in_bf, w_bf, nIn8, nW8);

    gemm_bt_kernel<<<dim3(OUT / BN, M / BM), 256, 0, stream>>>(
        in_bf, w_bf, bias, out, M, OUT, IN);
}